// Round 7
// baseline (428.284 us; speedup 1.0000x reference)
//
#include <hip/hip_runtime.h>
#include <hip/hip_bf16.h>
#include <cstdint>
#include <cstddef>

// ArcFace FC: out[i][j] = S * (j==label[i] ? phi(cos_ij) : cos_ij)
// cos = normalize(x) @ normalize(W)^T,  B=512, D=512, C=100000
//
// v8 = v6 (best: invw pre-pass + fp32-W global_load_lds + post-ds_read cvt)
// with the K-loop synchronization rebuilt as a counted-vmcnt 3-buffer
// pipeline (T4): raw s_barrier + s_waitcnt vmcnt(6), loads live across TWO
// iterations, vmcnt never drains to 0 in the loop. v6's __syncthreads
// (= vmcnt(0) drain each iter) was the structural stall: Mfma 12%, hbm 22%.
// v7's in-loop ||w|| accumulation is REVERTED (serial VALU chain on the
// critical path cost +50us; pre-pass costs only 33us).

#define SSCALE 30.0f
#define COSM_  0.8775825618903728f
#define SINM_  0.4794255386042030f
#define TH_    (-0.8775825618903728f)
#define MM_    0.2397127693021015f
#define EPS_   1e-12f

typedef unsigned short ushort_t;
typedef __attribute__((ext_vector_type(8))) short bf16x8;
typedef __attribute__((ext_vector_type(16))) float f32x16;

__device__ inline ushort_t f2bf(float f) {
    union { float f; unsigned u; } x; x.f = f;
    unsigned r = (x.u + 0x7fffu + ((x.u >> 16) & 1u)) >> 16;
    return (ushort_t)r;
}

__device__ inline ushort_t bfbits(float f) {
    union { __hip_bfloat16 h; ushort_t u; } c;
    c.h = __float2bfloat16(f);
    return c.u;
}

__device__ inline bf16x8 cvt8(float4 a, float4 b) {
    bf16x8 r;
    r[0] = (short)bfbits(a.x); r[1] = (short)bfbits(a.y);
    r[2] = (short)bfbits(a.z); r[3] = (short)bfbits(a.w);
    r[4] = (short)bfbits(b.x); r[5] = (short)bfbits(b.y);
    r[6] = (short)bfbits(b.z); r[7] = (short)bfbits(b.w);
    return r;
}

// ---- pre-pass: rows<C -> invw[row] only; rows>=C -> x normalized to bf16 ----
__global__ __launch_bounds__(256) void norm_inv_all(const float* __restrict__ x,
                                                    const float* __restrict__ w,
                                                    ushort_t* __restrict__ xn,
                                                    float* __restrict__ invw,
                                                    int C, int Bsz) {
    int rowg = blockIdx.x * 4 + (threadIdx.x >> 6);
    if (rowg >= C + Bsz) return;
    int lane = threadIdx.x & 63;
    const float* src = (rowg < C) ? w + (size_t)rowg * 512
                                  : x + (size_t)(rowg - C) * 512;
    float4 a = ((const float4*)src)[lane];
    float4 b = ((const float4*)src)[lane + 64];
    float ss = a.x*a.x + a.y*a.y + a.z*a.z + a.w*a.w
             + b.x*b.x + b.y*b.y + b.z*b.z + b.w*b.w;
    #pragma unroll
    for (int off = 32; off > 0; off >>= 1) ss += __shfl_down(ss, off, 64);
    if (rowg < C) {
        if (lane == 0) invw[rowg] = 1.0f / fmaxf(sqrtf(ss), EPS_);
        return;
    }
    ss = __shfl(ss, 0, 64);
    float inv = 1.0f / fmaxf(sqrtf(ss), EPS_);
    ushort_t* d = xn + (size_t)(rowg - C) * 512;
    union { ushort_t u[4]; uint2 v; } oa, ob;
    oa.u[0] = f2bf(a.x * inv); oa.u[1] = f2bf(a.y * inv);
    oa.u[2] = f2bf(a.z * inv); oa.u[3] = f2bf(a.w * inv);
    ob.u[0] = f2bf(b.x * inv); ob.u[1] = f2bf(b.y * inv);
    ob.u[2] = f2bf(b.z * inv); ob.u[3] = f2bf(b.w * inv);
    ((uint2*)d)[lane]      = oa.v;
    ((uint2*)d)[lane + 64] = ob.v;
}

// ---------------- fused GEMM: out = S * A @ (W * invw)^T --------------------
// A[M,K] normalized bf16; W[N,K] raw fp32; 128x128 tile, BK=32, 4 waves,
// each 64x64 via 2x2 of mfma_f32_32x32x16_bf16 (2 k-steps of 16).
// lA (bf16): 128 rows x 4 chunks(16B), chunk ^= (row>>1)&3.
// lB (fp32): 128 rows x 8 chunks(16B), chunk ^= row&7.
// TRIPLE-buffered; per iter: s_waitcnt vmcnt(6) [tile t landed, t+1 in
// flight], raw s_barrier, STAGE(t+2), compute(t). 6 VMEM ops per STAGE and
// none elsewhere in the loop keeps the vmcnt arithmetic exact.
__global__ __launch_bounds__(256) void gemm_fused(const ushort_t* __restrict__ A,
                                                  const float* __restrict__ W,
                                                  const float* __restrict__ invw,
                                                  float* __restrict__ out,
                                                  int M, int N, int K) {
    __shared__ ushort_t lA[3][128 * 32];   // 3 x 8 KB
    __shared__ float    lB[3][128 * 32];   // 3 x 16 KB
    int tid  = threadIdx.x;
    int wave = tid >> 6, lane = tid & 63;
    int half = lane >> 5, n5 = lane & 31;

    // XCD-chunked bijective remap (bm fastest within an XCD chunk)
    int nwg = gridDim.x;
    int nbm = M >> 7;
    int q = nwg >> 3, r = nwg & 7;
    int xcd = blockIdx.x & 7, pos = blockIdx.x >> 3;
    int logical = (xcd < r ? xcd * (q + 1) : r * (q + 1) + (xcd - r) * q) + pos;
    int bm = logical % nbm;
    int bn = logical / nbm;

    f32x16 acc[2][2];
    #pragma unroll
    for (int mt = 0; mt < 2; mt++)
        #pragma unroll
        for (int nt = 0; nt < 2; nt++)
            #pragma unroll
            for (int r2 = 0; r2 < 16; r2++)
                acc[mt][nt][r2] = 0.f;

    // A staging (2 x glds16): slot s = tid + 256*i -> row s>>2, stored chunk
    // s&3; source chunk = (s&3) ^ ((row>>1)&3) = (tid&3) ^ ((tid>>3)&3).
    int arow = tid >> 2;
    int ac0  = (tid & 3) ^ ((tid >> 3) & 3);
    const ushort_t* ag0 = A + (size_t)(bm * 128 + arow) * K + ac0 * 8;
    const ushort_t* ag1 = ag0 + (size_t)64 * K;

    // W staging (4 x glds16): slot s = tid + 256*i -> row s>>3 = (tid>>3)+32i,
    // stored chunk s&7; source chunk = (s&7) ^ (row&7) = (tid&7) ^ ((tid>>3)&7).
    int wrow = tid >> 3;
    int wc   = (tid & 7) ^ (wrow & 7);
    const float* wg[4];
    #pragma unroll
    for (int i = 0; i < 4; i++) {
        int rg = bn * 128 + wrow + 32 * i;
        if (rg > N - 1) rg = N - 1;
        wg[i] = W + (size_t)rg * K + wc * 4;
    }

    // fragment read addressing
    int swA  = (n5 >> 1) & 3;
    int ca0  = (half ^ swA) * 8;               // ks=0 chunk (ushorts)
    int ca1  = ((2 ^ half) ^ swA) * 8;         // ks=1
    int baseA = ((wave >> 1) * 64 + n5) * 32;  // ushort idx
    int r8   = n5 & 7;
    int baseB = ((wave & 1) * 64 + n5) * 32;   // float idx (row = 32 floats)

#define GLDS(gp, lp) __builtin_amdgcn_global_load_lds(                         \
        (const __attribute__((address_space(1))) void*)(gp),                   \
        (__attribute__((address_space(3))) void*)(lp), 16, 0, 0)

#define STAGE(b, k0) do {                                                      \
    GLDS(ag0 + (k0), &lA[b][wave * 512]);                                      \
    GLDS(ag1 + (k0), &lA[b][2048 + wave * 512]);                               \
    GLDS(wg[0] + (k0), &lB[b][wave * 256]);                                    \
    GLDS(wg[1] + (k0), &lB[b][1024 + wave * 256]);                             \
    GLDS(wg[2] + (k0), &lB[b][2048 + wave * 256]);                             \
    GLDS(wg[3] + (k0), &lB[b][3072 + wave * 256]);                             \
} while (0)

#define COMPUTE(b) do {                                                        \
    bf16x8 af[2][2], bfr[2][2];                                                \
    _Pragma("unroll")                                                          \
    for (int mt = 0; mt < 2; mt++) {                                           \
        af[mt][0] = *(const bf16x8*)&lA[b][baseA + mt * 1024 + ca0];           \
        af[mt][1] = *(const bf16x8*)&lA[b][baseA + mt * 1024 + ca1];           \
    }                                                                          \
    _Pragma("unroll")                                                          \
    for (int nt = 0; nt < 2; nt++) {                                           \
        _Pragma("unroll")                                                      \
        for (int ks = 0; ks < 2; ks++) {                                       \
            int p0 = (ks * 4 + half * 2) ^ r8;                                 \
            float4 f0 = *(const float4*)&lB[b][baseB + nt * 1024 + (p0 << 2)]; \
            float4 f1 = *(const float4*)&lB[b][baseB + nt * 1024 + ((p0 ^ 1) << 2)]; \
            bfr[nt][ks] = cvt8(f0, f1);                                        \
        }                                                                      \
    }                                                                          \
    _Pragma("unroll")                                                          \
    for (int ks = 0; ks < 2; ks++)                                             \
        _Pragma("unroll")                                                      \
        for (int mt = 0; mt < 2; mt++)                                         \
            _Pragma("unroll")                                                  \
            for (int nt = 0; nt < 2; nt++)                                     \
                acc[mt][nt] = __builtin_amdgcn_mfma_f32_32x32x16_bf16(         \
                    af[mt][ks], bfr[nt][ks], acc[mt][nt], 0, 0, 0);            \
} while (0)

    const int NT = K >> 5;                 // 16 for K=512 (NT >= 2 required)
    STAGE(0, 0);
    STAGE(1, 32);

    int cb = 0, sb = 2;
    for (int t = 0; t < NT - 1; ++t) {
        asm volatile("s_waitcnt vmcnt(6)" ::: "memory");
        __builtin_amdgcn_s_barrier();
        if (t + 2 < NT) {
            STAGE(sb, (t + 2) << 5);
        }
        COMPUTE(cb);
        cb = (cb == 2) ? 0 : cb + 1;
        sb = (sb == 2) ? 0 : sb + 1;
    }
    asm volatile("s_waitcnt vmcnt(0)" ::: "memory");
    __builtin_amdgcn_s_barrier();
    COMPUTE(cb);

#undef STAGE
#undef COMPUTE
#undef GLDS

    // epilogue: 32x32 C/D layout col = lane&31, row = (reg&3)+8*(reg>>2)+4*half
    int row0 = bm * 128 + (wave >> 1) * 64 + 4 * half;
    int col0 = bn * 128 + (wave & 1) * 64 + n5;
    #pragma unroll
    for (int nt = 0; nt < 2; nt++) {
        int c = col0 + nt * 32;
        if (c < N) {
            float sc = invw[c] * SSCALE;
            #pragma unroll
            for (int mt = 0; mt < 2; mt++) {
                #pragma unroll
                for (int r2 = 0; r2 < 16; r2++) {
                    int row = row0 + mt * 32 + (r2 & 3) + 8 * (r2 >> 2);
                    __builtin_nontemporal_store(acc[mt][nt][r2] * sc,
                                                &out[(size_t)row * N + c]);
                }
            }
        }
    }
}

// ---------------- fixup: apply arcface margin at (i, label[i]) ---------------
__global__ void fixup_kernel(const int* __restrict__ label, float* __restrict__ out,
                             int Bsz, int C) {
    int i = blockIdx.x * blockDim.x + threadIdx.x;
    if (i >= Bsz) return;
    int j = label[i];
    size_t idx = (size_t)i * C + j;
    float cosv = out[idx] * (1.0f / SSCALE);
    float sinv = sqrtf(fmaxf(0.f, 1.f - cosv * cosv));
    float phi = cosv * COSM_ - sinv * SINM_;
    if (!(cosv > TH_)) phi = cosv - MM_;
    out[idx] = phi * SSCALE;
}

// ---------------- fallback path (workspace too small / odd shapes) ----------
__global__ __launch_bounds__(256) void rownorm_inv(const float* __restrict__ in,
                                                   float* __restrict__ invn, int nrows) {
    int row = blockIdx.x * 4 + (threadIdx.x >> 6);
    if (row >= nrows) return;
    int lane = threadIdx.x & 63;
    const float4* p = (const float4*)(in + (size_t)row * 512);
    float4 a = p[lane];
    float4 b = p[lane + 64];
    float ss = a.x*a.x + a.y*a.y + a.z*a.z + a.w*a.w
             + b.x*b.x + b.y*b.y + b.z*b.z + b.w*b.w;
    #pragma unroll
    for (int off = 32; off > 0; off >>= 1) ss += __shfl_down(ss, off, 64);
    if (lane == 0) invn[row] = 1.0f / fmaxf(sqrtf(ss), EPS_);
}

__global__ __launch_bounds__(256) void naive_gemm(const float* __restrict__ x,
                                                  const float* __restrict__ w,
                                                  const float* __restrict__ invx,
                                                  const float* __restrict__ invw,
                                                  float* __restrict__ out, int Bsz, int C) {
    __shared__ float xs[512];
    int i = blockIdx.y;
    int j = blockIdx.x * 256 + threadIdx.x;
    for (int k = threadIdx.x; k < 512; k += 256) xs[k] = x[(size_t)i * 512 + k];
    __syncthreads();
    if (j >= C) return;
    const float* wr = w + (size_t)j * 512;
    float acc = 0.f;
    for (int k = 0; k < 512; k++) acc += xs[k] * wr[k];
    out[(size_t)i * C + j] = acc * invx[i] * invw[j] * SSCALE;
}

extern "C" void kernel_launch(void* const* d_in, const int* in_sizes, int n_in,
                              void* d_out, int out_size, void* d_ws, size_t ws_size,
                              hipStream_t stream) {
    const float* x = (const float*)d_in[0];
    const float* w = (const float*)d_in[1];
    const int* label = (const int*)d_in[2];
    float* out = (float*)d_out;

    const int Bsz = in_sizes[2];            // 512
    const int D   = 512;
    const int C   = in_sizes[1] / D;        // 100000

    size_t need = (size_t)Bsz * D * sizeof(ushort_t) + (size_t)C * sizeof(float);
    if (ws_size >= need && (Bsz % 128) == 0) {
        ushort_t* xn = (ushort_t*)d_ws;
        float* invw = (float*)(xn + (size_t)Bsz * D);
        norm_inv_all<<<(C + Bsz + 3) / 4, 256, 0, stream>>>(x, w, xn, invw, C, Bsz);
        int nbm = Bsz / 128, nbn = (C + 127) / 128;
        gemm_fused<<<nbm * nbn, 256, 0, stream>>>(xn, w, invw, out, Bsz, C, D);
    } else {
        float* invx = (float*)d_ws;
        float* invw = invx + Bsz;
        rownorm_inv<<<(Bsz + 3) / 4, 256, 0, stream>>>(x, invx, Bsz);
        rownorm_inv<<<(C + 3) / 4, 256, 0, stream>>>(w, invw, C);
        dim3 g((C + 255) / 256, Bsz);
        naive_gemm<<<g, 256, 0, stream>>>(x, w, invx, invw, out, Bsz, C);
    }
    fixup_kernel<<<(Bsz + 255) / 256, 256, 0, stream>>>(label, out, Bsz, C);
}

// Round 8
// 404.398 us; speedup vs baseline: 1.0591x; 1.0591x over previous
//
#include <hip/hip_runtime.h>
#include <hip/hip_bf16.h>
#include <cstdint>
#include <cstddef>

// ArcFace FC: out[i][j] = S * (j==label[i] ? phi(cos_ij) : cos_ij)
// cos = normalize(x) @ normalize(W)^T,  B=512, D=512, C=100000
//
// v9 = v8's counted-vmcnt pipeline at v6's occupancy: TWO buffers (48 KB ->
// 3 blocks/CU, was 72 KB -> 2) with the depth kept by barrier placement:
//   iter t: vmcnt(6) [tile t landed, t+1 stays in flight]; s_barrier;
//           COMPUTE(t); s_barrier; STAGE(t+2 -> buf[t&1]).
// vmcnt never drains to 0 in the loop; the second raw barrier (no drain)
// only fences buffer reuse. v8 evidence: pipeline raised MfmaUtil 12->16.4
// but 2 blocks/CU (Occupancy 20%) canceled it; v6 evidence: 3 blocks/CU
// with per-iter drain gave ~118us. This takes both.

#define SSCALE 30.0f
#define COSM_  0.8775825618903728f
#define SINM_  0.4794255386042030f
#define TH_    (-0.8775825618903728f)
#define MM_    0.2397127693021015f
#define EPS_   1e-12f

typedef unsigned short ushort_t;
typedef __attribute__((ext_vector_type(8))) short bf16x8;
typedef __attribute__((ext_vector_type(16))) float f32x16;

__device__ inline ushort_t f2bf(float f) {
    union { float f; unsigned u; } x; x.f = f;
    unsigned r = (x.u + 0x7fffu + ((x.u >> 16) & 1u)) >> 16;
    return (ushort_t)r;
}

__device__ inline ushort_t bfbits(float f) {
    union { __hip_bfloat16 h; ushort_t u; } c;
    c.h = __float2bfloat16(f);
    return c.u;
}

__device__ inline bf16x8 cvt8(float4 a, float4 b) {
    bf16x8 r;
    r[0] = (short)bfbits(a.x); r[1] = (short)bfbits(a.y);
    r[2] = (short)bfbits(a.z); r[3] = (short)bfbits(a.w);
    r[4] = (short)bfbits(b.x); r[5] = (short)bfbits(b.y);
    r[6] = (short)bfbits(b.z); r[7] = (short)bfbits(b.w);
    return r;
}

// ---- pre-pass: rows<C -> invw[row] only; rows>=C -> x normalized to bf16 ----
__global__ __launch_bounds__(256) void norm_inv_all(const float* __restrict__ x,
                                                    const float* __restrict__ w,
                                                    ushort_t* __restrict__ xn,
                                                    float* __restrict__ invw,
                                                    int C, int Bsz) {
    int rowg = blockIdx.x * 4 + (threadIdx.x >> 6);
    if (rowg >= C + Bsz) return;
    int lane = threadIdx.x & 63;
    const float* src = (rowg < C) ? w + (size_t)rowg * 512
                                  : x + (size_t)(rowg - C) * 512;
    float4 a = ((const float4*)src)[lane];
    float4 b = ((const float4*)src)[lane + 64];
    float ss = a.x*a.x + a.y*a.y + a.z*a.z + a.w*a.w
             + b.x*b.x + b.y*b.y + b.z*b.z + b.w*b.w;
    #pragma unroll
    for (int off = 32; off > 0; off >>= 1) ss += __shfl_down(ss, off, 64);
    if (rowg < C) {
        if (lane == 0) invw[rowg] = 1.0f / fmaxf(sqrtf(ss), EPS_);
        return;
    }
    ss = __shfl(ss, 0, 64);
    float inv = 1.0f / fmaxf(sqrtf(ss), EPS_);
    ushort_t* d = xn + (size_t)(rowg - C) * 512;
    union { ushort_t u[4]; uint2 v; } oa, ob;
    oa.u[0] = f2bf(a.x * inv); oa.u[1] = f2bf(a.y * inv);
    oa.u[2] = f2bf(a.z * inv); oa.u[3] = f2bf(a.w * inv);
    ob.u[0] = f2bf(b.x * inv); ob.u[1] = f2bf(b.y * inv);
    ob.u[2] = f2bf(b.z * inv); ob.u[3] = f2bf(b.w * inv);
    ((uint2*)d)[lane]      = oa.v;
    ((uint2*)d)[lane + 64] = ob.v;
}

// ---------------- fused GEMM: out = S * A @ (W * invw)^T --------------------
// A[M,K] normalized bf16; W[N,K] raw fp32; 128x128 tile, BK=32, 4 waves,
// each 64x64 via 2x2 of mfma_f32_32x32x16_bf16 (2 k-steps of 16).
// lA (bf16): 128 rows x 4 chunks(16B), chunk ^= (row>>1)&3.
// lB (fp32): 128 rows x 8 chunks(16B), chunk ^= row&7.
// DOUBLE-buffered, counted vmcnt: 6 VMEM ops per STAGE, none elsewhere.
__global__ __launch_bounds__(256) void gemm_fused(const ushort_t* __restrict__ A,
                                                  const float* __restrict__ W,
                                                  const float* __restrict__ invw,
                                                  float* __restrict__ out,
                                                  int M, int N, int K) {
    __shared__ ushort_t lA[2][128 * 32];   // 2 x 8 KB
    __shared__ float    lB[2][128 * 32];   // 2 x 16 KB
    int tid  = threadIdx.x;
    int wave = tid >> 6, lane = tid & 63;
    int half = lane >> 5, n5 = lane & 31;

    // XCD-chunked bijective remap (bm fastest within an XCD chunk)
    int nwg = gridDim.x;
    int nbm = M >> 7;
    int q = nwg >> 3, r = nwg & 7;
    int xcd = blockIdx.x & 7, pos = blockIdx.x >> 3;
    int logical = (xcd < r ? xcd * (q + 1) : r * (q + 1) + (xcd - r) * q) + pos;
    int bm = logical % nbm;
    int bn = logical / nbm;

    f32x16 acc[2][2];
    #pragma unroll
    for (int mt = 0; mt < 2; mt++)
        #pragma unroll
        for (int nt = 0; nt < 2; nt++)
            #pragma unroll
            for (int r2 = 0; r2 < 16; r2++)
                acc[mt][nt][r2] = 0.f;

    // A staging (2 x glds16): slot s = tid + 256*i -> row s>>2, stored chunk
    // s&3; source chunk = (s&3) ^ ((row>>1)&3) = (tid&3) ^ ((tid>>3)&3).
    int arow = tid >> 2;
    int ac0  = (tid & 3) ^ ((tid >> 3) & 3);
    const ushort_t* ag0 = A + (size_t)(bm * 128 + arow) * K + ac0 * 8;
    const ushort_t* ag1 = ag0 + (size_t)64 * K;

    // W staging (4 x glds16): slot s = tid + 256*i -> row s>>3 = (tid>>3)+32i,
    // stored chunk s&7; source chunk = (s&7) ^ (row&7) = (tid&7) ^ ((tid>>3)&7).
    int wrow = tid >> 3;
    int wc   = (tid & 7) ^ (wrow & 7);
    const float* wg[4];
    #pragma unroll
    for (int i = 0; i < 4; i++) {
        int rg = bn * 128 + wrow + 32 * i;
        if (rg > N - 1) rg = N - 1;
        wg[i] = W + (size_t)rg * K + wc * 4;
    }

    // fragment read addressing
    int swA  = (n5 >> 1) & 3;
    int ca0  = (half ^ swA) * 8;               // ks=0 chunk (ushorts)
    int ca1  = ((2 ^ half) ^ swA) * 8;         // ks=1
    int baseA = ((wave >> 1) * 64 + n5) * 32;  // ushort idx
    int r8   = n5 & 7;
    int baseB = ((wave & 1) * 64 + n5) * 32;   // float idx (row = 32 floats)

#define GLDS(gp, lp) __builtin_amdgcn_global_load_lds(                         \
        (const __attribute__((address_space(1))) void*)(gp),                   \
        (__attribute__((address_space(3))) void*)(lp), 16, 0, 0)

#define STAGE(b, k0) do {                                                      \
    GLDS(ag0 + (k0), &lA[b][wave * 512]);                                      \
    GLDS(ag1 + (k0), &lA[b][2048 + wave * 512]);                               \
    GLDS(wg[0] + (k0), &lB[b][wave * 256]);                                    \
    GLDS(wg[1] + (k0), &lB[b][1024 + wave * 256]);                             \
    GLDS(wg[2] + (k0), &lB[b][2048 + wave * 256]);                             \
    GLDS(wg[3] + (k0), &lB[b][3072 + wave * 256]);                             \
} while (0)

#define COMPUTE(b) do {                                                        \
    bf16x8 af[2][2], bfr[2][2];                                                \
    _Pragma("unroll")                                                          \
    for (int mt = 0; mt < 2; mt++) {                                           \
        af[mt][0] = *(const bf16x8*)&lA[b][baseA + mt * 1024 + ca0];           \
        af[mt][1] = *(const bf16x8*)&lA[b][baseA + mt * 1024 + ca1];           \
    }                                                                          \
    _Pragma("unroll")                                                          \
    for (int nt = 0; nt < 2; nt++) {                                           \
        _Pragma("unroll")                                                      \
        for (int ks = 0; ks < 2; ks++) {                                       \
            int p0 = (ks * 4 + half * 2) ^ r8;                                 \
            float4 f0 = *(const float4*)&lB[b][baseB + nt * 1024 + (p0 << 2)]; \
            float4 f1 = *(const float4*)&lB[b][baseB + nt * 1024 + ((p0 ^ 1) << 2)]; \
            bfr[nt][ks] = cvt8(f0, f1);                                        \
        }                                                                      \
    }                                                                          \
    _Pragma("unroll")                                                          \
    for (int ks = 0; ks < 2; ks++)                                             \
        _Pragma("unroll")                                                      \
        for (int mt = 0; mt < 2; mt++)                                         \
            _Pragma("unroll")                                                  \
            for (int nt = 0; nt < 2; nt++)                                     \
                acc[mt][nt] = __builtin_amdgcn_mfma_f32_32x32x16_bf16(         \
                    af[mt][ks], bfr[nt][ks], acc[mt][nt], 0, 0, 0);            \
} while (0)

    const int NT = K >> 5;                 // 16 for K=512 (needs NT >= 2)
    STAGE(0, 0);
    STAGE(1, 32);

    for (int t = 0; t < NT; ++t) {
        if (t < NT - 1) {
            asm volatile("s_waitcnt vmcnt(6)" ::: "memory");  // tile t landed
        } else {
            asm volatile("s_waitcnt vmcnt(0)" ::: "memory");  // final tile
        }
        __builtin_amdgcn_s_barrier();      // all waves' tile-t loads landed
        COMPUTE(t & 1);
        if (t + 2 < NT) {
            __builtin_amdgcn_s_barrier();  // all waves done reading buf[t&1]
            STAGE(t & 1, (t + 2) << 5);    // t+1 stays in flight throughout
        }
    }

#undef STAGE
#undef COMPUTE
#undef GLDS

    // epilogue: 32x32 C/D layout col = lane&31, row = (reg&3)+8*(reg>>2)+4*half
    int row0 = bm * 128 + (wave >> 1) * 64 + 4 * half;
    int col0 = bn * 128 + (wave & 1) * 64 + n5;
    #pragma unroll
    for (int nt = 0; nt < 2; nt++) {
        int c = col0 + nt * 32;
        if (c < N) {
            float sc = invw[c] * SSCALE;
            #pragma unroll
            for (int mt = 0; mt < 2; mt++) {
                #pragma unroll
                for (int r2 = 0; r2 < 16; r2++) {
                    int row = row0 + mt * 32 + (r2 & 3) + 8 * (r2 >> 2);
                    __builtin_nontemporal_store(acc[mt][nt][r2] * sc,
                                                &out[(size_t)row * N + c]);
                }
            }
        }
    }
}

// ---------------- fixup: apply arcface margin at (i, label[i]) ---------------
__global__ void fixup_kernel(const int* __restrict__ label, float* __restrict__ out,
                             int Bsz, int C) {
    int i = blockIdx.x * blockDim.x + threadIdx.x;
    if (i >= Bsz) return;
    int j = label[i];
    size_t idx = (size_t)i * C + j;
    float cosv = out[idx] * (1.0f / SSCALE);
    float sinv = sqrtf(fmaxf(0.f, 1.f - cosv * cosv));
    float phi = cosv * COSM_ - sinv * SINM_;
    if (!(cosv > TH_)) phi = cosv - MM_;
    out[idx] = phi * SSCALE;
}

// ---------------- fallback path (workspace too small / odd shapes) ----------
__global__ __launch_bounds__(256) void rownorm_inv(const float* __restrict__ in,
                                                   float* __restrict__ invn, int nrows) {
    int row = blockIdx.x * 4 + (threadIdx.x >> 6);
    if (row >= nrows) return;
    int lane = threadIdx.x & 63;
    const float4* p = (const float4*)(in + (size_t)row * 512);
    float4 a = p[lane];
    float4 b = p[lane + 64];
    float ss = a.x*a.x + a.y*a.y + a.z*a.z + a.w*a.w
             + b.x*b.x + b.y*b.y + b.z*b.z + b.w*b.w;
    #pragma unroll
    for (int off = 32; off > 0; off >>= 1) ss += __shfl_down(ss, off, 64);
    if (lane == 0) invn[row] = 1.0f / fmaxf(sqrtf(ss), EPS_);
}

__global__ __launch_bounds__(256) void naive_gemm(const float* __restrict__ x,
                                                  const float* __restrict__ w,
                                                  const float* __restrict__ invx,
                                                  const float* __restrict__ invw,
                                                  float* __restrict__ out, int Bsz, int C) {
    __shared__ float xs[512];
    int i = blockIdx.y;
    int j = blockIdx.x * 256 + threadIdx.x;
    for (int k = threadIdx.x; k < 512; k += 256) xs[k] = x[(size_t)i * 512 + k];
    __syncthreads();
    if (j >= C) return;
    const float* wr = w + (size_t)j * 512;
    float acc = 0.f;
    for (int k = 0; k < 512; k++) acc += xs[k] * wr[k];
    out[(size_t)i * C + j] = acc * invx[i] * invw[j] * SSCALE;
}

extern "C" void kernel_launch(void* const* d_in, const int* in_sizes, int n_in,
                              void* d_out, int out_size, void* d_ws, size_t ws_size,
                              hipStream_t stream) {
    const float* x = (const float*)d_in[0];
    const float* w = (const float*)d_in[1];
    const int* label = (const int*)d_in[2];
    float* out = (float*)d_out;

    const int Bsz = in_sizes[2];            // 512
    const int D   = 512;
    const int C   = in_sizes[1] / D;        // 100000

    size_t need = (size_t)Bsz * D * sizeof(ushort_t) + (size_t)C * sizeof(float);
    if (ws_size >= need && (Bsz % 128) == 0) {
        ushort_t* xn = (ushort_t*)d_ws;
        float* invw = (float*)(xn + (size_t)Bsz * D);
        norm_inv_all<<<(C + Bsz + 3) / 4, 256, 0, stream>>>(x, w, xn, invw, C, Bsz);
        int nbm = Bsz / 128, nbn = (C + 127) / 128;
        gemm_fused<<<nbm * nbn, 256, 0, stream>>>(xn, w, invw, out, Bsz, C, D);
    } else {
        float* invx = (float*)d_ws;
        float* invw = invx + Bsz;
        rownorm_inv<<<(Bsz + 3) / 4, 256, 0, stream>>>(x, invx, Bsz);
        rownorm_inv<<<(C + 3) / 4, 256, 0, stream>>>(w, invw, C);
        dim3 g((C + 255) / 256, Bsz);
        naive_gemm<<<g, 256, 0, stream>>>(x, w, invx, invw, out, Bsz, C);
    }
    fixup_kernel<<<(Bsz + 255) / 256, 256, 0, stream>>>(label, out, Bsz, C);
}